// Round 19
// baseline (847.642 us; speedup 1.0000x reference)
//
#include <hip/hip_runtime.h>
#include <hip/hip_bf16.h>
#include <math.h>

typedef __hip_bfloat16 bf16;
typedef __attribute__((ext_vector_type(4))) float f32x4;
typedef __attribute__((ext_vector_type(8))) short short8;
typedef __attribute__((ext_vector_type(4))) short short4v;

#define BATCH   8192
#define NTOT    65536      // 8 chunks * BATCH
#define NT2     131072     // 2 frames * NTOT (enc2 out)
#define NW      262144     // 8 chunks * 4 frames * BATCH
#define HID     128

__device__ __forceinline__ float b2f(bf16 v){ return __bfloat162float(v); }
__device__ __forceinline__ bf16  f2b(float v){ return __float2bfloat16(v); }
__device__ __forceinline__ short f2bs(float v){
  bf16 b = __float2bfloat16(v);
  return *reinterpret_cast<short*>(&b);
}
__device__ __forceinline__ float sigf(float x){ return 1.0f/(1.0f+__expf(-x)); }
__device__ __forceinline__ float tanhfast(float x){
  return 1.0f - 2.0f/(__expf(2.0f*x)+1.0f);
}

// ---------------------------------------------------------------------------
// Weight conversion (hi/lo split: W = hi + lo, lo = bf16(W - hi))
// ---------------------------------------------------------------------------
__global__ __launch_bounds__(256) void k_wcvt(        // stft W -> bf16 [258][256]
    const float* __restrict__ W, bf16* __restrict__ Wb)
{
  const int idx = blockIdx.x*256 + threadIdx.x;
  if (idx < 258*256) Wb[idx] = f2b(W[idx]);
}
__global__ __launch_bounds__(256) void k_w1cvt(       // w1 -> [3][128][320] hi|lo
    const float* __restrict__ w1, bf16* __restrict__ w1b)
{
  const int idx = blockIdx.x*256 + threadIdx.x;       // 3*128*320 = 122880
  if (idx >= 122880) return;
  const int dt = idx / 40960, rem = idx % 40960;
  const int cout = rem / 320, k = rem % 320;
  const int kk = (k >= 160) ? (k - 160) : k;
  const float v = (kk < 129) ? w1[(cout*129 + kk)*3 + dt] : 0.f;
  const bf16 hi = f2b(v);
  w1b[idx] = (k >= 160) ? f2b(v - b2f(hi)) : hi;
}
__global__ __launch_bounds__(256) void k_w2cvt(       // w2 -> [3][64][256] hi|lo
    const float* __restrict__ w2, bf16* __restrict__ w2b)
{
  const int idx = blockIdx.x*256 + threadIdx.x;       // 3*64*256 = 49152
  if (idx >= 49152) return;
  const int dt = idx >> 14, cout = (idx >> 8) & 63, k = idx & 255;
  const int kk = k & 127;
  const float v = w2[(cout*128 + kk)*3 + dt];
  const bf16 hi = f2b(v);
  w2b[idx] = (k >= 128) ? f2b(v - b2f(hi)) : hi;
}
// enc3 taps 1,2 -> w3e[64][256] hi|lo; enc4 center -> w4e[128][128] hi|lo
__global__ __launch_bounds__(256) void k_w34cvt(
    const float* __restrict__ w3, const float* __restrict__ w4,
    bf16* __restrict__ w3e, bf16* __restrict__ w4e)
{
  const int idx = blockIdx.x*256 + threadIdx.x;       // 32768
  if (idx >= 32768) return;
  if (idx < 16384){
    const int row = idx >> 8, k = idx & 255;
    const int kk = k & 127, cin = kk >> 1, t = kk & 1;
    const float v = w3[(row*64 + cin)*3 + 1 + t];
    const bf16 hi = f2b(v);
    w3e[idx] = (k >= 128) ? f2b(v - b2f(hi)) : hi;
  } else {
    const int i2 = idx - 16384;
    const int row = i2 >> 7, k = i2 & 127;
    const int cin = k & 63;
    const float v = w4[(row*64 + cin)*3 + 1];
    const bf16 hi = f2b(v);
    w4e[i2] = (k >= 64) ? f2b(v - b2f(hi)) : hi;
  }
}
// Whh-only recurrent weights -> [512][384]: [Whh_hi | Whh_hi | Whh_lo]
__global__ __launch_bounds__(256) void k_wlcvt3(
    const float* __restrict__ whh, bf16* __restrict__ wl3)
{
  const int idx = blockIdx.x*256 + threadIdx.x;       // 512*384 = 196608
  if (idx >= 196608) return;
  const int r = idx / 384, k = idx % 384;
  const int part = k >> 7, kk = k & 127;
  const float f = whh[r*128 + kk];
  const bf16 hi = f2b(f);
  wl3[idx] = (part < 2) ? hi : f2b(f - b2f(hi));
}
// Wih hi/lo planes: wlx[2][512][128]
__global__ __launch_bounds__(256) void k_wlxcvt(
    const float* __restrict__ wih, bf16* __restrict__ wlx)
{
  const int idx = blockIdx.x*256 + threadIdx.x;       // 131072
  if (idx >= 131072) return;
  const int pl = idx >> 16, rem = idx & 65535;
  const float f = wih[rem];
  const bf16 hi = f2b(f);
  wlx[idx] = (pl == 0) ? hi : f2b(f - b2f(hi));
}

// ---------------------------------------------------------------------------
// K1 v5: STFT MFMA GEMM with per-pass A-tile staged in LDS (48 KB), shared
// by all 4 waves — converts the 144 per-lane L2 A-loads into 12 staged
// coalesced loads + LDS reads. B fragments as validated r13. mag [129][NW].
// ---------------------------------------------------------------------------
__global__ __launch_bounds__(256) void k_stft3(
    const float* __restrict__ audio, const bf16* __restrict__ Wb,
    bf16* __restrict__ mag)
{
  __shared__ __align__(16) char ALDS[96*512];      // 48 KB
  __shared__ __align__(16) bf16 refl[4*8*64];      // 4 KB
  const int tid = threadIdx.x, lane = tid & 63, wq = tid >> 6;
  const int r0 = blockIdx.x * 4;                   // 2048 blocks
  const float* arow = audio + (size_t)(r0 + wq) * 4160;

  #pragma unroll
  for (int q = 0; q < 8; ++q){
    const int e = q*64 + lane;
    const int i = e >> 6, k = e & 63;
    refl[(wq*8 + i)*64 + k] = f2b(arow[512*i + 64 - k]);
  }

  const int kgo8 = (lane>>4)*8;
  short8 Bfrag[2][8];
  #pragma unroll
  for (int ng = 0; ng < 2; ++ng){
    const int wl = ng*16 + (lane & 15);
    const int i = wl >> 2, t = wl & 3;
    #pragma unroll
    for (int ks = 0; ks < 8; ++ks){
      const int kb = ks*32 + kgo8;
      if (t == 0 && kb < 64){
        Bfrag[ng][ks] = *(const short8*)(refl + (wq*8 + i)*64 + kb);
      } else {
        const float* src = arow + 512*i + 128*t - 64 + kb;
        const float4 v0 = *(const float4*)(src);
        const float4 v1 = *(const float4*)(src + 4);
        short8 s;
        s[0]=f2bs(v0.x); s[1]=f2bs(v0.y); s[2]=f2bs(v0.z); s[3]=f2bs(v0.w);
        s[4]=f2bs(v1.x); s[5]=f2bs(v1.y); s[6]=f2bs(v1.z); s[7]=f2bs(v1.w);
        Bfrag[ng][ks] = s;
      }
    }
  }

  const int kab = (lane>>4)*16;
  for (int pass = 0; pass < 3; ++pass){
    __syncthreads();                               // ALDS consumers of prev pass done
    // stage A tile: rows ar = b3*32 + reim*16 + bl  (48 bins x Re/Im)
    for (int idx = tid; idx < 96*32; idx += 256){
      const int ar = idx >> 5;                     // 0..95
      const int cb = (idx & 31) * 16;              // byte 0..496
      const int b3 = ar >> 5, reim = (ar >> 4) & 1, bl = ar & 15;
      int bin = pass*48 + b3*16 + bl;
      if (bin > 128) bin = 128;
      const int grow = bin + reim*129;
      int off = ar*512 + cb; off ^= ((ar&7)<<4);
      *(f32x4*)(ALDS + off) = *(const f32x4*)((const char*)Wb + grow*512 + cb);
    }
    __syncthreads();

    f32x4 accRe[3][2], accIm[3][2];
    #pragma unroll
    for (int b3 = 0; b3 < 3; ++b3)
      #pragma unroll
      for (int ng = 0; ng < 2; ++ng){
        accRe[b3][ng] = f32x4{0.f,0.f,0.f,0.f};
        accIm[b3][ng] = f32x4{0.f,0.f,0.f,0.f};
      }
    #pragma unroll
    for (int ks = 0; ks < 8; ++ks){
      #pragma unroll
      for (int b3 = 0; b3 < 3; ++b3){
        const int arRe = b3*32 + (lane & 15);
        const int arIm = arRe + 16;
        int offRe = arRe*512 + ks*64 + kab; offRe ^= ((arRe&7)<<4);
        int offIm = arIm*512 + ks*64 + kab; offIm ^= ((arIm&7)<<4);
        const short8 aRe = *(const short8*)(ALDS + offRe);
        const short8 aIm = *(const short8*)(ALDS + offIm);
        #pragma unroll
        for (int ng = 0; ng < 2; ++ng){
          accRe[b3][ng] = __builtin_amdgcn_mfma_f32_16x16x32_bf16(
              aRe, Bfrag[ng][ks], accRe[b3][ng], 0, 0, 0);
          accIm[b3][ng] = __builtin_amdgcn_mfma_f32_16x16x32_bf16(
              aIm, Bfrag[ng][ks], accIm[b3][ng], 0, 0, 0);
        }
      }
    }
    #pragma unroll
    for (int b3 = 0; b3 < 3; ++b3)
      #pragma unroll
      for (int j = 0; j < 4; ++j){
        const int bin = (pass*3 + b3)*16 + (lane>>4)*4 + j;
        if (bin <= 128){
          #pragma unroll
          for (int ng = 0; ng < 2; ++ng){
            const int wl = ng*16 + (lane & 15);
            const int i = wl >> 2, t = wl & 3;
            const float re = accRe[b3][ng][j], im = accIm[b3][ng][j];
            mag[(size_t)bin*NW + (size_t)i*32768 + (r0+wq)*4 + t] =
                f2b(sqrtf(re*re + im*im));
          }
        }
      }
  }
}

// ---------------------------------------------------------------------------
// K2: enc1 MFMA GEMM hi/lo (validated r13). h1 [128][NW].
// ---------------------------------------------------------------------------
#define E1_LDS (192*320)
__global__ __launch_bounds__(256) void k_enc1_gemm(
    const bf16* __restrict__ mag, const bf16* __restrict__ w1b,
    const float* __restrict__ b1, bf16* __restrict__ h1)
{
  __shared__ __align__(16) char Bs[E1_LDS];
  const int tid = threadIdx.x, lane = tid & 63, wq = tid >> 6;
  const int n0 = blockIdx.x * 32;
  const int i  = n0 >> 13, b0 = n0 & 8191;
  const size_t colbase = (size_t)i*32768 + (size_t)b0*4;

  for (int off = tid*16; off < E1_LDS; off += 256*16)
    *(f32x4*)(Bs + off) = f32x4{0.f,0.f,0.f,0.f};
  __syncthreads();
  for (int it = tid; it < 129*64; it += 256){
    const int cin = it >> 6, seg = it & 63;
    const unsigned int pair =
        *(const unsigned int*)(mag + (size_t)cin*NW + colbase + seg*2);
    #pragma unroll
    for (int q = 0; q < 2; ++q){
      const int w = seg*2 + q;
      const int row = (w>>2)*6 + (w&3) + 1;
      int off = row*320 + cin*2; off ^= ((row&7)<<4);
      *(short*)(Bs + off) = (short)((q==0) ? (pair & 0xffff) : (pair >> 16));
    }
  }
  __syncthreads();

  const int wr = wq >> 1, wc = wq & 1;
  f32x4 acc[4][4];
  #pragma unroll
  for (int mg = 0; mg < 4; ++mg)
    #pragma unroll
    for (int ng = 0; ng < 4; ++ng) acc[mg][ng] = f32x4{0.f,0.f,0.f,0.f};

  int brow[4], acol[4];
  #pragma unroll
  for (int ng = 0; ng < 4; ++ng){
    const int w = wc*64 + ng*16 + (lane & 15);
    brow[ng] = (w>>2)*6 + (w&3);
  }
  #pragma unroll
  for (int mg = 0; mg < 4; ++mg) acol[mg] = wr*64 + mg*16 + (lane & 15);
  const int kb = (lane>>4)*16;

  for (int dt = 0; dt < 3; ++dt){
    #pragma unroll
    for (int ks = 0; ks < 5; ++ks){
      short8 afrH[4], afrL[4], bfr[4];
      #pragma unroll
      for (int mg = 0; mg < 4; ++mg){
        const char* base = (const char*)w1b +
            ((dt*128 + acol[mg])*320 + ks*32)*2 + kb;
        afrH[mg] = *(const short8*)base;
        afrL[mg] = *(const short8*)(base + 320);
      }
      #pragma unroll
      for (int ng = 0; ng < 4; ++ng){
        const int row = brow[ng] + dt;
        int off = row*320 + ks*64 + kb; off ^= ((row&7)<<4);
        bfr[ng] = *(const short8*)(Bs + off);
      }
      #pragma unroll
      for (int mg = 0; mg < 4; ++mg)
        #pragma unroll
        for (int ng = 0; ng < 4; ++ng){
          acc[mg][ng] = __builtin_amdgcn_mfma_f32_16x16x32_bf16(
              afrH[mg], bfr[ng], acc[mg][ng], 0, 0, 0);
          acc[mg][ng] = __builtin_amdgcn_mfma_f32_16x16x32_bf16(
              afrL[mg], bfr[ng], acc[mg][ng], 0, 0, 0);
        }
    }
  }
  #pragma unroll
  for (int mg = 0; mg < 4; ++mg)
    #pragma unroll
    for (int j = 0; j < 4; ++j){
      const int cout = wr*64 + mg*16 + (lane>>4)*4 + j;
      const float bv = b1[cout];
      #pragma unroll
      for (int ng = 0; ng < 4; ++ng){
        const int col = wc*64 + ng*16 + (lane & 15);
        float v = acc[mg][ng][j] + bv; v = v > 0.f ? v : 0.f;
        h1[(size_t)cout*NW + colbase + col] = f2b(v);
      }
    }
}

// ---------------------------------------------------------------------------
// K3: enc2 MFMA GEMM hi/lo (validated). h2 [64][NT2].
// ---------------------------------------------------------------------------
#define E2_LDS (160*256)
__global__ __launch_bounds__(256) void k_enc2_gemm(
    const bf16* __restrict__ h1, const bf16* __restrict__ w2b,
    const float* __restrict__ b2, bf16* __restrict__ h2)
{
  __shared__ __align__(16) char Bs[E2_LDS];
  const int tid = threadIdx.x, lane = tid & 63, wq = tid >> 6;
  const int n0 = blockIdx.x * 32;
  const int i  = n0 >> 13, b0 = n0 & 8191;
  const size_t colbase = (size_t)i*32768 + (size_t)b0*4;
  const size_t col2base = (size_t)i*16384 + (size_t)b0*2;

  for (int off = tid*16; off < E2_LDS; off += 256*16)
    *(f32x4*)(Bs + off) = f32x4{0.f,0.f,0.f,0.f};
  __syncthreads();
  for (int it = tid; it < 128*64; it += 256){
    const int cin = it >> 6, seg = it & 63;
    const unsigned int pair =
        *(const unsigned int*)(h1 + (size_t)cin*NW + colbase + seg*2);
    #pragma unroll
    for (int q = 0; q < 2; ++q){
      const int w = seg*2 + q;
      const int row = (w>>2)*5 + (w&3) + 1;
      int off = row*256 + cin*2; off ^= ((row&7)<<4);
      *(short*)(Bs + off) = (short)((q==0) ? (pair & 0xffff) : (pair >> 16));
    }
  }
  __syncthreads();

  const int wr = wq >> 1, wc = wq & 1;
  f32x4 acc[2][2];
  #pragma unroll
  for (int mg = 0; mg < 2; ++mg)
    #pragma unroll
    for (int ng = 0; ng < 2; ++ng) acc[mg][ng] = f32x4{0.f,0.f,0.f,0.f};

  int brow[2], acol[2];
  #pragma unroll
  for (int ng = 0; ng < 2; ++ng){
    const int wl = wc*32 + ng*16 + (lane & 15);
    brow[ng] = (wl>>1)*5 + (wl&1)*2;
  }
  #pragma unroll
  for (int mg = 0; mg < 2; ++mg) acol[mg] = wr*32 + mg*16 + (lane & 15);
  const int kb = (lane>>4)*16;

  for (int dt = 0; dt < 3; ++dt){
    #pragma unroll
    for (int ks = 0; ks < 4; ++ks){
      short8 afrH[2], afrL[2], bfr[2];
      #pragma unroll
      for (int mg = 0; mg < 2; ++mg){
        const char* base = (const char*)w2b +
            ((dt*64 + acol[mg])*256 + ks*32)*2 + kb;
        afrH[mg] = *(const short8*)base;
        afrL[mg] = *(const short8*)(base + 256);
      }
      #pragma unroll
      for (int ng = 0; ng < 2; ++ng){
        const int row = brow[ng] + dt;
        int off = row*256 + ks*64 + kb; off ^= ((row&7)<<4);
        bfr[ng] = *(const short8*)(Bs + off);
      }
      #pragma unroll
      for (int mg = 0; mg < 2; ++mg)
        #pragma unroll
        for (int ng = 0; ng < 2; ++ng){
          acc[mg][ng] = __builtin_amdgcn_mfma_f32_16x16x32_bf16(
              afrH[mg], bfr[ng], acc[mg][ng], 0, 0, 0);
          acc[mg][ng] = __builtin_amdgcn_mfma_f32_16x16x32_bf16(
              afrL[mg], bfr[ng], acc[mg][ng], 0, 0, 0);
        }
    }
  }
  #pragma unroll
  for (int mg = 0; mg < 2; ++mg)
    #pragma unroll
    for (int j = 0; j < 4; ++j){
      const int cout = wr*32 + mg*16 + (lane>>4)*4 + j;
      const float bv = b2[cout];
      #pragma unroll
      for (int ng = 0; ng < 2; ++ng){
        const int col = wc*32 + ng*16 + (lane & 15);
        float v = acc[mg][ng][j] + bv; v = v > 0.f ? v : 0.f;
        h2[(size_t)cout*NT2 + col2base + col] = f2b(v);
      }
    }
}

// ---------------------------------------------------------------------------
// K4+K5 FUSED: enc3 -> enc4 MFMA (validated r18). h4 [128][NTOT].
// ---------------------------------------------------------------------------
__global__ __launch_bounds__(256) void k_enc34(
    const bf16* __restrict__ h2, const bf16* __restrict__ w3e,
    const float* __restrict__ b3, const bf16* __restrict__ w4e,
    const float* __restrict__ b4, bf16* __restrict__ h4)
{
  __shared__ __align__(16) char B1[64*256];       // 16 KB
  __shared__ __align__(16) char B2[64*128];       //  8 KB
  const int tid = threadIdx.x, lane = tid & 63, wq = tid >> 6;
  const int n0 = blockIdx.x * 64;                 // 1024 blocks

  for (int it = tid; it < 64*64; it += 256){
    const int cin = it >> 6, nl = it & 63;
    const int n = n0 + nl, i = n >> 13, b = n & 8191;
    const unsigned int pair =
        *(const unsigned int*)(h2 + (size_t)cin*NT2 + i*16384 + 2*b);
    int off = nl*256 + cin*4; off ^= ((nl&7)<<4);
    *(unsigned int*)(B1 + off) = pair;
  }
  __syncthreads();

  const int kb = (lane>>4)*16;
  f32x4 acc1[4];
  #pragma unroll
  for (int ng = 0; ng < 4; ++ng) acc1[ng] = f32x4{0.f,0.f,0.f,0.f};
  const int ar1 = wq*16 + (lane & 15);
  #pragma unroll
  for (int ks = 0; ks < 8; ++ks){
    const short8 a = *(const short8*)((const char*)w3e + (ar1*256 + ks*32)*2 + kb);
    #pragma unroll
    for (int ng = 0; ng < 4; ++ng){
      const int row = ng*16 + (lane & 15);
      int off = row*256 + (ks&3)*64 + kb; off ^= ((row&7)<<4);
      const short8 bfr = *(const short8*)(B1 + off);
      acc1[ng] = __builtin_amdgcn_mfma_f32_16x16x32_bf16(a, bfr, acc1[ng], 0, 0, 0);
    }
  }
  #pragma unroll
  for (int j = 0; j < 4; ++j){
    const int r1 = wq*16 + (lane>>4)*4 + j;
    const float bv = b3[r1];
    #pragma unroll
    for (int ng = 0; ng < 4; ++ng){
      const int col = ng*16 + (lane & 15);
      float v = acc1[ng][j] + bv; v = v > 0.f ? v : 0.f;
      int off = col*128 + r1*2; off ^= ((col&7)<<4);
      *(short*)(B2 + off) = f2bs(v);
    }
  }
  __syncthreads();

  f32x4 acc2[2][4];
  #pragma unroll
  for (int mg = 0; mg < 2; ++mg)
    #pragma unroll
    for (int ng = 0; ng < 4; ++ng) acc2[mg][ng] = f32x4{0.f,0.f,0.f,0.f};
  #pragma unroll
  for (int ks = 0; ks < 4; ++ks){
    short8 bfr[4];
    #pragma unroll
    for (int ng = 0; ng < 4; ++ng){
      const int row = ng*16 + (lane & 15);
      int off = row*128 + (ks&1)*64 + kb; off ^= ((row&7)<<4);
      bfr[ng] = *(const short8*)(B2 + off);
    }
    #pragma unroll
    for (int mg = 0; mg < 2; ++mg){
      const int ar2 = wq*32 + mg*16 + (lane & 15);
      const short8 a = *(const short8*)((const char*)w4e + (ar2*128 + ks*32)*2 + kb);
      #pragma unroll
      for (int ng = 0; ng < 4; ++ng)
        acc2[mg][ng] = __builtin_amdgcn_mfma_f32_16x16x32_bf16(a, bfr[ng], acc2[mg][ng], 0, 0, 0);
    }
  }
  #pragma unroll
  for (int mg = 0; mg < 2; ++mg)
    #pragma unroll
    for (int j = 0; j < 4; ++j){
      const int cout = wq*32 + mg*16 + (lane>>4)*4 + j;
      const float bv = b4[cout];
      #pragma unroll
      for (int ng = 0; ng < 4; ++ng){
        const int n = n0 + ng*16 + (lane & 15);
        float v = acc2[mg][ng][j] + bv; v = v > 0.f ? v : 0.f;
        h4[(size_t)cout*NTOT + n] = f2b(v);
      }
    }
}

// K6: transpose h0/c0 [B,128] -> [128][B]
__global__ __launch_bounds__(256) void k_init(
    const float* __restrict__ h0, const float* __restrict__ c0,
    float* __restrict__ hT0, float* __restrict__ cT)
{
  const int idx = blockIdx.x*256 + threadIdx.x;   // 1M
  const int b = idx >> 7, c = idx & 127;
  hT0[c*BATCH + b] = h0[idx];
  cT [c*BATCH + b] = c0[idx];
}

// ---------------------------------------------------------------------------
// K-GX: xg[512][32768] = Wih @ x for 4 steps (one half).
// ---------------------------------------------------------------------------
__global__ __launch_bounds__(256) void k_gatex(
    const bf16* __restrict__ h4, const bf16* __restrict__ wlx,
    float* __restrict__ xg, int half)
{
  __shared__ __align__(16) char Bs[32*256];
  const int tid = threadIdx.x, lane = tid & 63, wq = tid >> 6;
  const int n0 = blockIdx.x * 32;
  const int gcol = half*32768 + n0;

  for (int it = tid; it < 128*32; it += 256){
    const int cp = it >> 5, nl = it & 31;
    const bf16 v = h4[(size_t)cp*NTOT + gcol + nl];
    int off = nl*256 + cp*2; off ^= ((nl&7)<<4);
    *(short*)(Bs + off) = *(const short*)&v;
  }
  __syncthreads();

  f32x4 acc[8][2];
  #pragma unroll
  for (int mg = 0; mg < 8; ++mg)
    #pragma unroll
    for (int ng = 0; ng < 2; ++ng) acc[mg][ng] = f32x4{0.f,0.f,0.f,0.f};

  int arow[8];
  #pragma unroll
  for (int mg = 0; mg < 8; ++mg) arow[mg] = wq*128 + mg*16 + (lane & 15);
  const int kb = (lane>>4)*16;

  #pragma unroll
  for (int ks = 0; ks < 4; ++ks){
    short8 bfr[2];
    #pragma unroll
    for (int ng = 0; ng < 2; ++ng){
      const int row = ng*16 + (lane & 15);
      int off = row*256 + ks*64 + kb; off ^= ((row&7)<<4);
      bfr[ng] = *(const short8*)(Bs + off);
    }
    #pragma unroll
    for (int pl = 0; pl < 2; ++pl)
      #pragma unroll
      for (int mg = 0; mg < 8; ++mg){
        const short8 a = *(const short8*)((const char*)wlx +
            ((size_t)(pl*512 + arow[mg])*128 + ks*32)*2 + kb);
        #pragma unroll
        for (int ng = 0; ng < 2; ++ng)
          acc[mg][ng] = __builtin_amdgcn_mfma_f32_16x16x32_bf16(
              a, bfr[ng], acc[mg][ng], 0, 0, 0);
      }
  }

  #pragma unroll
  for (int mg = 0; mg < 8; ++mg)
    #pragma unroll
    for (int j = 0; j < 4; ++j){
      const int row = wq*128 + mg*16 + (lane>>4)*4 + j;
      #pragma unroll
      for (int ng = 0; ng < 2; ++ng){
        const int col = n0 + ng*16 + (lane & 15);
        xg[(size_t)row*32768 + col] = acc[mg][ng][j];
      }
    }
}

// ---------------------------------------------------------------------------
// K7 v2: one recurrent LSTM step, Whh-only MFMA (K=384), 16 batch cols per
// block (512 blocks = 2 blocks/CU, 2x latency-hiding vs r18's 256x32).
// ---------------------------------------------------------------------------
__global__ __launch_bounds__(256) void k_lstm_rec(
    const float* __restrict__ xg, const bf16* __restrict__ wl3,
    const float* __restrict__ bih, const float* __restrict__ bhh,
    const float* __restrict__ hprev, float* __restrict__ hout,
    float* __restrict__ cT, int s)
{
  __shared__ __align__(16) char Bs[16*768];       // 12 KB
  const int tid = threadIdx.x, lane = tid & 63, wq = tid >> 6;
  const int b0 = blockIdx.x * 16;                 // 512 blocks

  for (int it = tid; it < 128*16; it += 256){
    const int cp = it >> 4, bl = it & 15;
    const float v = hprev[cp*BATCH + b0 + bl];
    const bf16 hi = f2b(v);
    const bf16 lo = f2b(v - b2f(hi));
    int off1 = bl*768 + cp*2;        off1 ^= ((bl&7)<<4);
    int off2 = bl*768 + (128+cp)*2;  off2 ^= ((bl&7)<<4);
    int off3 = bl*768 + (256+cp)*2;  off3 ^= ((bl&7)<<4);
    *(short*)(Bs + off1) = *(const short*)&hi;
    *(short*)(Bs + off2) = *(const short*)&lo;
    *(short*)(Bs + off3) = *(const short*)&hi;
  }
  __syncthreads();

  const int c0r = wq*32;
  f32x4 acc[4][2];
  #pragma unroll
  for (int g = 0; g < 4; ++g)
    #pragma unroll
    for (int h = 0; h < 2; ++h) acc[g][h] = f32x4{0.f,0.f,0.f,0.f};

  int arow[4][2];
  #pragma unroll
  for (int g = 0; g < 4; ++g)
    #pragma unroll
    for (int h = 0; h < 2; ++h)
      arow[g][h] = (g*128 + c0r + h*16 + (lane&15))*768 + (lane>>4)*16;

  #pragma unroll
  for (int ks = 0; ks < 12; ++ks){
    const int row = lane & 15;
    int boff = row*768 + ks*64 + (lane>>4)*16; boff ^= ((row&7)<<4);
    const short8 bfr = *(const short8*)(Bs + boff);
    #pragma unroll
    for (int g = 0; g < 4; ++g)
      #pragma unroll
      for (int h = 0; h < 2; ++h){
        const short8 a = *(const short8*)((const char*)wl3 + arow[g][h] + ks*64);
        acc[g][h] = __builtin_amdgcn_mfma_f32_16x16x32_bf16(
            a, bfr, acc[g][h], 0, 0, 0);
      }
  }

  const size_t xcolbase = (size_t)(s & 3)*8192 + b0;
  #pragma unroll
  for (int h = 0; h < 2; ++h)
    #pragma unroll
    for (int j = 0; j < 4; ++j){
      const int c = c0r + h*16 + (lane>>4)*4 + j;
      const int b = b0 + (lane & 15);
      const size_t xc = xcolbase + (lane & 15);
      const float ig = acc[0][h][j] + xg[(size_t)(0*128+c)*32768 + xc] + bih[c]       + bhh[c];
      const float fg = acc[1][h][j] + xg[(size_t)(1*128+c)*32768 + xc] + bih[128 + c] + bhh[128 + c];
      const float gg = acc[2][h][j] + xg[(size_t)(2*128+c)*32768 + xc] + bih[256 + c] + bhh[256 + c];
      const float og = acc[3][h][j] + xg[(size_t)(3*128+c)*32768 + xc] + bih[384 + c] + bhh[384 + c];
      const float cold = cT[c*BATCH + b];
      const float cn = sigf(fg)*cold + sigf(ig)*tanhfast(gg);
      const float hn = sigf(og)*tanhfast(cn);
      cT  [c*BATCH + b] = cn;
      hout[c*BATCH + b] = hn;
    }
}

// K8a: P[s][b] = sigmoid(ow . hseq[s][:,b] + ob)
__global__ __launch_bounds__(256) void k_headp(
    const float* __restrict__ hseq, const float* __restrict__ ow,
    const float* __restrict__ ob, float* __restrict__ P)
{
  const int idx = blockIdx.x*256 + threadIdx.x;   // 65536
  const int s = idx >> 13, b = idx & (BATCH-1);
  const float* hp = hseq + (size_t)s*HID*BATCH;
  float acc = ob[0];
  for (int c = 0; c < 128; ++c) acc += ow[c]*hp[c*BATCH + b];
  P[s*BATCH + b] = sigf(acc);
}
// K8b: final = 1 - prod(1 - P[s])
__global__ __launch_bounds__(256) void k_head2(
    const float* __restrict__ P, float* __restrict__ outp)
{
  const int b = blockIdx.x*256 + threadIdx.x;     // 8192
  float prod = 1.f;
  #pragma unroll
  for (int s = 0; s < 8; ++s) prod *= (1.f - P[s*BATCH + b]);
  outp[b] = 1.f - prod;
}

// K9: transpose h_fin, c_fin to [B,128] in d_out
__global__ __launch_bounds__(256) void k_outT(
    const float* __restrict__ h7, const float* __restrict__ cT,
    float* __restrict__ out)
{
  const int idx = blockIdx.x*256 + threadIdx.x;   // 1M
  const int b = idx >> 7, c = idx & 127;
  out[8192 + idx]           = h7[c*BATCH + b];
  out[8192 + 1048576 + idx] = cT[c*BATCH + b];
}

// ---------------------------------------------------------------------------
extern "C" void kernel_launch(void* const* d_in, const int* in_sizes, int n_in,
                              void* d_out, int out_size, void* d_ws, size_t ws_size,
                              hipStream_t stream)
{
  (void)in_sizes; (void)n_in; (void)out_size; (void)ws_size;
  const float* audio = (const float*)d_in[0];
  const float* h0    = (const float*)d_in[1];
  const float* c0    = (const float*)d_in[2];
  const float* stftw = (const float*)d_in[3];
  const float* w1 = (const float*)d_in[4];  const float* b1 = (const float*)d_in[5];
  const float* w2 = (const float*)d_in[6];  const float* b2 = (const float*)d_in[7];
  const float* w3 = (const float*)d_in[8];  const float* b3 = (const float*)d_in[9];
  const float* w4 = (const float*)d_in[10]; const float* b4 = (const float*)d_in[11];
  const float* wih = (const float*)d_in[12]; const float* whh = (const float*)d_in[13];
  const float* bih = (const float*)d_in[14]; const float* bhh = (const float*)d_in[15];
  const float* ow  = (const float*)d_in[16]; const float* ob  = (const float*)d_in[17];
  float* out = (float*)d_out;

  // Workspace schedule (validated r18):
  char* ws = (char*)d_ws;
  bf16*  mag  = (bf16*) (ws + 0);
  bf16*  w2b  = (bf16*) (ws + 0);
  bf16*  w3e  = (bf16*) (ws + 1048576);
  bf16*  w4e  = (bf16*) (ws + 1081344);
  bf16*  h4   = (bf16*) (ws + 8388608);
  float* xg   = (float*)(ws + 25165824);
  float* hseq = (float*)(ws + 92274688);
  float* hT0  = (float*)(ws + 125829120);
  float* cT   = (float*)(ws + 130023424);
  bf16*  h1   = (bf16*) (ws + 67633152);
  bf16*  Wbf  = (bf16*) (ws + 67633152);
  bf16*  h2   = (bf16*) (ws + 134742016);
  bf16*  w1b  = (bf16*) (ws + 134742016);
  bf16*  wl3  = (bf16*) (ws + 134742016);
  bf16*  wlx  = (bf16*) (ws + 135135232);
  float* Pbuf = (float*)(ws + 135397376);

  k_wcvt  <<<258, 256, 0, stream>>>(stftw, Wbf);
  k_w1cvt <<<480, 256, 0, stream>>>(w1, w1b);
  k_stft3<<<2048, 256, 0, stream>>>(audio, Wbf, mag);
  k_enc1_gemm<<<2048, 256, 0, stream>>>(mag, w1b, b1, h1);
  k_w2cvt <<<192, 256, 0, stream>>>(w2, w2b);           // after enc1: mag dead
  k_w34cvt<<<128, 256, 0, stream>>>(w3, w4, w3e, w4e);  // after enc1: mag dead
  k_enc2_gemm<<<2048, 256, 0, stream>>>(h1, w2b, b2, h2);
  k_init <<<4096, 256, 0, stream>>>(h0, c0, hT0, cT);   // after enc2: h1 dead
  k_enc34<<<1024, 256, 0, stream>>>(h2, w3e, b3, w4e, b4, h4);
  k_wlcvt3<<<768, 256, 0, stream>>>(whh, wl3);          // after enc34: h2 dead
  k_wlxcvt<<<512, 256, 0, stream>>>(wih, wlx);
  for (int half = 0; half < 2; ++half){
    k_gatex<<<1024, 256, 0, stream>>>(h4, wlx, xg, half);
    for (int q = 0; q < 4; ++q){
      const int s = half*4 + q;
      const float* hprev = (s == 0) ? hT0 : (hseq + (size_t)(s-1)*HID*BATCH);
      k_lstm_rec<<<512, 256, 0, stream>>>(xg, wl3, bih, bhh, hprev,
                                          hseq + (size_t)s*HID*BATCH, cT, s);
    }
  }
  k_headp<<<256, 256, 0, stream>>>(hseq, ow, ob, Pbuf);
  k_head2<<<32, 256, 0, stream>>>(Pbuf, out);
  k_outT<<<4096, 256, 0, stream>>>(hseq + (size_t)7*HID*BATCH, cT, out);
}

// Round 20
// 713.206 us; speedup vs baseline: 1.1885x; 1.1885x over previous
//
#include <hip/hip_runtime.h>
#include <hip/hip_bf16.h>
#include <math.h>

typedef __hip_bfloat16 bf16;
typedef __attribute__((ext_vector_type(4))) float f32x4;
typedef __attribute__((ext_vector_type(8))) short short8;
typedef __attribute__((ext_vector_type(4))) short short4v;

#define BATCH   8192
#define NTOT    65536      // 8 chunks * BATCH
#define NT2     131072     // 2 frames * NTOT (enc2 out)
#define NW      262144     // 8 chunks * 4 frames * BATCH
#define HID     128

__device__ __forceinline__ float b2f(bf16 v){ return __bfloat162float(v); }
__device__ __forceinline__ bf16  f2b(float v){ return __float2bfloat16(v); }
__device__ __forceinline__ short f2bs(float v){
  bf16 b = __float2bfloat16(v);
  return *reinterpret_cast<short*>(&b);
}
__device__ __forceinline__ float sigf(float x){ return 1.0f/(1.0f+__expf(-x)); }
__device__ __forceinline__ float tanhfast(float x){
  return 1.0f - 2.0f/(__expf(2.0f*x)+1.0f);
}

// ---------------------------------------------------------------------------
// Weight conversion (hi/lo split: W = hi + lo, lo = bf16(W - hi))
// ---------------------------------------------------------------------------
__global__ __launch_bounds__(256) void k_wcvt(        // stft W -> bf16 [258][256]
    const float* __restrict__ W, bf16* __restrict__ Wb)
{
  const int idx = blockIdx.x*256 + threadIdx.x;
  if (idx < 258*256) Wb[idx] = f2b(W[idx]);
}
__global__ __launch_bounds__(256) void k_w1cvt(       // w1 -> [3][128][320] hi|lo
    const float* __restrict__ w1, bf16* __restrict__ w1b)
{
  const int idx = blockIdx.x*256 + threadIdx.x;       // 3*128*320 = 122880
  if (idx >= 122880) return;
  const int dt = idx / 40960, rem = idx % 40960;
  const int cout = rem / 320, k = rem % 320;
  const int kk = (k >= 160) ? (k - 160) : k;
  const float v = (kk < 129) ? w1[(cout*129 + kk)*3 + dt] : 0.f;
  const bf16 hi = f2b(v);
  w1b[idx] = (k >= 160) ? f2b(v - b2f(hi)) : hi;
}
__global__ __launch_bounds__(256) void k_w2cvt(       // w2 -> [3][64][256] hi|lo
    const float* __restrict__ w2, bf16* __restrict__ w2b)
{
  const int idx = blockIdx.x*256 + threadIdx.x;       // 3*64*256 = 49152
  if (idx >= 49152) return;
  const int dt = idx >> 14, cout = (idx >> 8) & 63, k = idx & 255;
  const int kk = k & 127;
  const float v = w2[(cout*128 + kk)*3 + dt];
  const bf16 hi = f2b(v);
  w2b[idx] = (k >= 128) ? f2b(v - b2f(hi)) : hi;
}
// enc3 taps 1,2 -> w3e[64][256] hi|lo; enc4 center -> w4e[128][128] hi|lo
__global__ __launch_bounds__(256) void k_w34cvt(
    const float* __restrict__ w3, const float* __restrict__ w4,
    bf16* __restrict__ w3e, bf16* __restrict__ w4e)
{
  const int idx = blockIdx.x*256 + threadIdx.x;       // 32768
  if (idx >= 32768) return;
  if (idx < 16384){
    const int row = idx >> 8, k = idx & 255;
    const int kk = k & 127, cin = kk >> 1, t = kk & 1;
    const float v = w3[(row*64 + cin)*3 + 1 + t];
    const bf16 hi = f2b(v);
    w3e[idx] = (k >= 128) ? f2b(v - b2f(hi)) : hi;
  } else {
    const int i2 = idx - 16384;
    const int row = i2 >> 7, k = i2 & 127;
    const int cin = k & 63;
    const float v = w4[(row*64 + cin)*3 + 1];
    const bf16 hi = f2b(v);
    w4e[i2] = (k >= 64) ? f2b(v - b2f(hi)) : hi;
  }
}
// Whh-only recurrent weights -> [512][384]: [Whh_hi | Whh_hi | Whh_lo]
__global__ __launch_bounds__(256) void k_wlcvt3(
    const float* __restrict__ whh, bf16* __restrict__ wl3)
{
  const int idx = blockIdx.x*256 + threadIdx.x;       // 512*384 = 196608
  if (idx >= 196608) return;
  const int r = idx / 384, k = idx % 384;
  const int part = k >> 7, kk = k & 127;
  const float f = whh[r*128 + kk];
  const bf16 hi = f2b(f);
  wl3[idx] = (part < 2) ? hi : f2b(f - b2f(hi));
}
// Wih hi/lo planes: wlx[2][512][128]
__global__ __launch_bounds__(256) void k_wlxcvt(
    const float* __restrict__ wih, bf16* __restrict__ wlx)
{
  const int idx = blockIdx.x*256 + threadIdx.x;       // 131072
  if (idx >= 131072) return;
  const int pl = idx >> 16, rem = idx & 65535;
  const float f = wih[rem];
  const bf16 hi = f2b(f);
  wlx[idx] = (pl == 0) ? hi : f2b(f - b2f(hi));
}

// ---------------------------------------------------------------------------
// K1 v5 (validated r19): STFT MFMA GEMM, per-pass A-tile staged in LDS.
// mag [129][NW].
// ---------------------------------------------------------------------------
__global__ __launch_bounds__(256) void k_stft3(
    const float* __restrict__ audio, const bf16* __restrict__ Wb,
    bf16* __restrict__ mag)
{
  __shared__ __align__(16) char ALDS[96*512];      // 48 KB
  __shared__ __align__(16) bf16 refl[4*8*64];      // 4 KB
  const int tid = threadIdx.x, lane = tid & 63, wq = tid >> 6;
  const int r0 = blockIdx.x * 4;                   // 2048 blocks
  const float* arow = audio + (size_t)(r0 + wq) * 4160;

  #pragma unroll
  for (int q = 0; q < 8; ++q){
    const int e = q*64 + lane;
    const int i = e >> 6, k = e & 63;
    refl[(wq*8 + i)*64 + k] = f2b(arow[512*i + 64 - k]);
  }

  const int kgo8 = (lane>>4)*8;
  short8 Bfrag[2][8];
  #pragma unroll
  for (int ng = 0; ng < 2; ++ng){
    const int wl = ng*16 + (lane & 15);
    const int i = wl >> 2, t = wl & 3;
    #pragma unroll
    for (int ks = 0; ks < 8; ++ks){
      const int kb = ks*32 + kgo8;
      if (t == 0 && kb < 64){
        Bfrag[ng][ks] = *(const short8*)(refl + (wq*8 + i)*64 + kb);
      } else {
        const float* src = arow + 512*i + 128*t - 64 + kb;
        const float4 v0 = *(const float4*)(src);
        const float4 v1 = *(const float4*)(src + 4);
        short8 s;
        s[0]=f2bs(v0.x); s[1]=f2bs(v0.y); s[2]=f2bs(v0.z); s[3]=f2bs(v0.w);
        s[4]=f2bs(v1.x); s[5]=f2bs(v1.y); s[6]=f2bs(v1.z); s[7]=f2bs(v1.w);
        Bfrag[ng][ks] = s;
      }
    }
  }

  const int kab = (lane>>4)*16;
  for (int pass = 0; pass < 3; ++pass){
    __syncthreads();
    for (int idx = tid; idx < 96*32; idx += 256){
      const int ar = idx >> 5;
      const int cb = (idx & 31) * 16;
      const int b3 = ar >> 5, reim = (ar >> 4) & 1, bl = ar & 15;
      int bin = pass*48 + b3*16 + bl;
      if (bin > 128) bin = 128;
      const int grow = bin + reim*129;
      int off = ar*512 + cb; off ^= ((ar&7)<<4);
      *(f32x4*)(ALDS + off) = *(const f32x4*)((const char*)Wb + grow*512 + cb);
    }
    __syncthreads();

    f32x4 accRe[3][2], accIm[3][2];
    #pragma unroll
    for (int b3 = 0; b3 < 3; ++b3)
      #pragma unroll
      for (int ng = 0; ng < 2; ++ng){
        accRe[b3][ng] = f32x4{0.f,0.f,0.f,0.f};
        accIm[b3][ng] = f32x4{0.f,0.f,0.f,0.f};
      }
    #pragma unroll
    for (int ks = 0; ks < 8; ++ks){
      #pragma unroll
      for (int b3 = 0; b3 < 3; ++b3){
        const int arRe = b3*32 + (lane & 15);
        const int arIm = arRe + 16;
        int offRe = arRe*512 + ks*64 + kab; offRe ^= ((arRe&7)<<4);
        int offIm = arIm*512 + ks*64 + kab; offIm ^= ((arIm&7)<<4);
        const short8 aRe = *(const short8*)(ALDS + offRe);
        const short8 aIm = *(const short8*)(ALDS + offIm);
        #pragma unroll
        for (int ng = 0; ng < 2; ++ng){
          accRe[b3][ng] = __builtin_amdgcn_mfma_f32_16x16x32_bf16(
              aRe, Bfrag[ng][ks], accRe[b3][ng], 0, 0, 0);
          accIm[b3][ng] = __builtin_amdgcn_mfma_f32_16x16x32_bf16(
              aIm, Bfrag[ng][ks], accIm[b3][ng], 0, 0, 0);
        }
      }
    }
    #pragma unroll
    for (int b3 = 0; b3 < 3; ++b3)
      #pragma unroll
      for (int j = 0; j < 4; ++j){
        const int bin = (pass*3 + b3)*16 + (lane>>4)*4 + j;
        if (bin <= 128){
          #pragma unroll
          for (int ng = 0; ng < 2; ++ng){
            const int wl = ng*16 + (lane & 15);
            const int i = wl >> 2, t = wl & 3;
            const float re = accRe[b3][ng][j], im = accIm[b3][ng][j];
            mag[(size_t)bin*NW + (size_t)i*32768 + (r0+wq)*4 + t] =
                f2b(sqrtf(re*re + im*im));
          }
        }
      }
  }
}

// ---------------------------------------------------------------------------
// K2: enc1 MFMA GEMM hi/lo (validated r13). h1 [128][NW].
// ---------------------------------------------------------------------------
#define E1_LDS (192*320)
__global__ __launch_bounds__(256) void k_enc1_gemm(
    const bf16* __restrict__ mag, const bf16* __restrict__ w1b,
    const float* __restrict__ b1, bf16* __restrict__ h1)
{
  __shared__ __align__(16) char Bs[E1_LDS];
  const int tid = threadIdx.x, lane = tid & 63, wq = tid >> 6;
  const int n0 = blockIdx.x * 32;
  const int i  = n0 >> 13, b0 = n0 & 8191;
  const size_t colbase = (size_t)i*32768 + (size_t)b0*4;

  for (int off = tid*16; off < E1_LDS; off += 256*16)
    *(f32x4*)(Bs + off) = f32x4{0.f,0.f,0.f,0.f};
  __syncthreads();
  for (int it = tid; it < 129*64; it += 256){
    const int cin = it >> 6, seg = it & 63;
    const unsigned int pair =
        *(const unsigned int*)(mag + (size_t)cin*NW + colbase + seg*2);
    #pragma unroll
    for (int q = 0; q < 2; ++q){
      const int w = seg*2 + q;
      const int row = (w>>2)*6 + (w&3) + 1;
      int off = row*320 + cin*2; off ^= ((row&7)<<4);
      *(short*)(Bs + off) = (short)((q==0) ? (pair & 0xffff) : (pair >> 16));
    }
  }
  __syncthreads();

  const int wr = wq >> 1, wc = wq & 1;
  f32x4 acc[4][4];
  #pragma unroll
  for (int mg = 0; mg < 4; ++mg)
    #pragma unroll
    for (int ng = 0; ng < 4; ++ng) acc[mg][ng] = f32x4{0.f,0.f,0.f,0.f};

  int brow[4], acol[4];
  #pragma unroll
  for (int ng = 0; ng < 4; ++ng){
    const int w = wc*64 + ng*16 + (lane & 15);
    brow[ng] = (w>>2)*6 + (w&3);
  }
  #pragma unroll
  for (int mg = 0; mg < 4; ++mg) acol[mg] = wr*64 + mg*16 + (lane & 15);
  const int kb = (lane>>4)*16;

  for (int dt = 0; dt < 3; ++dt){
    #pragma unroll
    for (int ks = 0; ks < 5; ++ks){
      short8 afrH[4], afrL[4], bfr[4];
      #pragma unroll
      for (int mg = 0; mg < 4; ++mg){
        const char* base = (const char*)w1b +
            ((dt*128 + acol[mg])*320 + ks*32)*2 + kb;
        afrH[mg] = *(const short8*)base;
        afrL[mg] = *(const short8*)(base + 320);
      }
      #pragma unroll
      for (int ng = 0; ng < 4; ++ng){
        const int row = brow[ng] + dt;
        int off = row*320 + ks*64 + kb; off ^= ((row&7)<<4);
        bfr[ng] = *(const short8*)(Bs + off);
      }
      #pragma unroll
      for (int mg = 0; mg < 4; ++mg)
        #pragma unroll
        for (int ng = 0; ng < 4; ++ng){
          acc[mg][ng] = __builtin_amdgcn_mfma_f32_16x16x32_bf16(
              afrH[mg], bfr[ng], acc[mg][ng], 0, 0, 0);
          acc[mg][ng] = __builtin_amdgcn_mfma_f32_16x16x32_bf16(
              afrL[mg], bfr[ng], acc[mg][ng], 0, 0, 0);
        }
    }
  }
  #pragma unroll
  for (int mg = 0; mg < 4; ++mg)
    #pragma unroll
    for (int j = 0; j < 4; ++j){
      const int cout = wr*64 + mg*16 + (lane>>4)*4 + j;
      const float bv = b1[cout];
      #pragma unroll
      for (int ng = 0; ng < 4; ++ng){
        const int col = wc*64 + ng*16 + (lane & 15);
        float v = acc[mg][ng][j] + bv; v = v > 0.f ? v : 0.f;
        h1[(size_t)cout*NW + colbase + col] = f2b(v);
      }
    }
}

// ---------------------------------------------------------------------------
// K3: enc2 MFMA GEMM hi/lo (validated). h2 [64][NT2].
// ---------------------------------------------------------------------------
#define E2_LDS (160*256)
__global__ __launch_bounds__(256) void k_enc2_gemm(
    const bf16* __restrict__ h1, const bf16* __restrict__ w2b,
    const float* __restrict__ b2, bf16* __restrict__ h2)
{
  __shared__ __align__(16) char Bs[E2_LDS];
  const int tid = threadIdx.x, lane = tid & 63, wq = tid >> 6;
  const int n0 = blockIdx.x * 32;
  const int i  = n0 >> 13, b0 = n0 & 8191;
  const size_t colbase = (size_t)i*32768 + (size_t)b0*4;
  const size_t col2base = (size_t)i*16384 + (size_t)b0*2;

  for (int off = tid*16; off < E2_LDS; off += 256*16)
    *(f32x4*)(Bs + off) = f32x4{0.f,0.f,0.f,0.f};
  __syncthreads();
  for (int it = tid; it < 128*64; it += 256){
    const int cin = it >> 6, seg = it & 63;
    const unsigned int pair =
        *(const unsigned int*)(h1 + (size_t)cin*NW + colbase + seg*2);
    #pragma unroll
    for (int q = 0; q < 2; ++q){
      const int w = seg*2 + q;
      const int row = (w>>2)*5 + (w&3) + 1;
      int off = row*256 + cin*2; off ^= ((row&7)<<4);
      *(short*)(Bs + off) = (short)((q==0) ? (pair & 0xffff) : (pair >> 16));
    }
  }
  __syncthreads();

  const int wr = wq >> 1, wc = wq & 1;
  f32x4 acc[2][2];
  #pragma unroll
  for (int mg = 0; mg < 2; ++mg)
    #pragma unroll
    for (int ng = 0; ng < 2; ++ng) acc[mg][ng] = f32x4{0.f,0.f,0.f,0.f};

  int brow[2], acol[2];
  #pragma unroll
  for (int ng = 0; ng < 2; ++ng){
    const int wl = wc*32 + ng*16 + (lane & 15);
    brow[ng] = (wl>>1)*5 + (wl&1)*2;
  }
  #pragma unroll
  for (int mg = 0; mg < 2; ++mg) acol[mg] = wr*32 + mg*16 + (lane & 15);
  const int kb = (lane>>4)*16;

  for (int dt = 0; dt < 3; ++dt){
    #pragma unroll
    for (int ks = 0; ks < 4; ++ks){
      short8 afrH[2], afrL[2], bfr[2];
      #pragma unroll
      for (int mg = 0; mg < 2; ++mg){
        const char* base = (const char*)w2b +
            ((dt*64 + acol[mg])*256 + ks*32)*2 + kb;
        afrH[mg] = *(const short8*)base;
        afrL[mg] = *(const short8*)(base + 256);
      }
      #pragma unroll
      for (int ng = 0; ng < 2; ++ng){
        const int row = brow[ng] + dt;
        int off = row*256 + ks*64 + kb; off ^= ((row&7)<<4);
        bfr[ng] = *(const short8*)(Bs + off);
      }
      #pragma unroll
      for (int mg = 0; mg < 2; ++mg)
        #pragma unroll
        for (int ng = 0; ng < 2; ++ng){
          acc[mg][ng] = __builtin_amdgcn_mfma_f32_16x16x32_bf16(
              afrH[mg], bfr[ng], acc[mg][ng], 0, 0, 0);
          acc[mg][ng] = __builtin_amdgcn_mfma_f32_16x16x32_bf16(
              afrL[mg], bfr[ng], acc[mg][ng], 0, 0, 0);
        }
    }
  }
  #pragma unroll
  for (int mg = 0; mg < 2; ++mg)
    #pragma unroll
    for (int j = 0; j < 4; ++j){
      const int cout = wr*32 + mg*16 + (lane>>4)*4 + j;
      const float bv = b2[cout];
      #pragma unroll
      for (int ng = 0; ng < 2; ++ng){
        const int col = wc*32 + ng*16 + (lane & 15);
        float v = acc[mg][ng][j] + bv; v = v > 0.f ? v : 0.f;
        h2[(size_t)cout*NT2 + col2base + col] = f2b(v);
      }
    }
}

// ---------------------------------------------------------------------------
// K4+K5 FUSED: enc3 -> enc4 MFMA (validated r18). h4 [128][NTOT].
// ---------------------------------------------------------------------------
__global__ __launch_bounds__(256) void k_enc34(
    const bf16* __restrict__ h2, const bf16* __restrict__ w3e,
    const float* __restrict__ b3, const bf16* __restrict__ w4e,
    const float* __restrict__ b4, bf16* __restrict__ h4)
{
  __shared__ __align__(16) char B1[64*256];       // 16 KB
  __shared__ __align__(16) char B2[64*128];       //  8 KB
  const int tid = threadIdx.x, lane = tid & 63, wq = tid >> 6;
  const int n0 = blockIdx.x * 64;                 // 1024 blocks

  for (int it = tid; it < 64*64; it += 256){
    const int cin = it >> 6, nl = it & 63;
    const int n = n0 + nl, i = n >> 13, b = n & 8191;
    const unsigned int pair =
        *(const unsigned int*)(h2 + (size_t)cin*NT2 + i*16384 + 2*b);
    int off = nl*256 + cin*4; off ^= ((nl&7)<<4);
    *(unsigned int*)(B1 + off) = pair;
  }
  __syncthreads();

  const int kb = (lane>>4)*16;
  f32x4 acc1[4];
  #pragma unroll
  for (int ng = 0; ng < 4; ++ng) acc1[ng] = f32x4{0.f,0.f,0.f,0.f};
  const int ar1 = wq*16 + (lane & 15);
  #pragma unroll
  for (int ks = 0; ks < 8; ++ks){
    const short8 a = *(const short8*)((const char*)w3e + (ar1*256 + ks*32)*2 + kb);
    #pragma unroll
    for (int ng = 0; ng < 4; ++ng){
      const int row = ng*16 + (lane & 15);
      int off = row*256 + (ks&3)*64 + kb; off ^= ((row&7)<<4);
      const short8 bfr = *(const short8*)(B1 + off);
      acc1[ng] = __builtin_amdgcn_mfma_f32_16x16x32_bf16(a, bfr, acc1[ng], 0, 0, 0);
    }
  }
  #pragma unroll
  for (int j = 0; j < 4; ++j){
    const int r1 = wq*16 + (lane>>4)*4 + j;
    const float bv = b3[r1];
    #pragma unroll
    for (int ng = 0; ng < 4; ++ng){
      const int col = ng*16 + (lane & 15);
      float v = acc1[ng][j] + bv; v = v > 0.f ? v : 0.f;
      int off = col*128 + r1*2; off ^= ((col&7)<<4);
      *(short*)(B2 + off) = f2bs(v);
    }
  }
  __syncthreads();

  f32x4 acc2[2][4];
  #pragma unroll
  for (int mg = 0; mg < 2; ++mg)
    #pragma unroll
    for (int ng = 0; ng < 4; ++ng) acc2[mg][ng] = f32x4{0.f,0.f,0.f,0.f};
  #pragma unroll
  for (int ks = 0; ks < 4; ++ks){
    short8 bfr[4];
    #pragma unroll
    for (int ng = 0; ng < 4; ++ng){
      const int row = ng*16 + (lane & 15);
      int off = row*128 + (ks&1)*64 + kb; off ^= ((row&7)<<4);
      bfr[ng] = *(const short8*)(B2 + off);
    }
    #pragma unroll
    for (int mg = 0; mg < 2; ++mg){
      const int ar2 = wq*32 + mg*16 + (lane & 15);
      const short8 a = *(const short8*)((const char*)w4e + (ar2*128 + ks*32)*2 + kb);
      #pragma unroll
      for (int ng = 0; ng < 4; ++ng)
        acc2[mg][ng] = __builtin_amdgcn_mfma_f32_16x16x32_bf16(a, bfr[ng], acc2[mg][ng], 0, 0, 0);
    }
  }
  #pragma unroll
  for (int mg = 0; mg < 2; ++mg)
    #pragma unroll
    for (int j = 0; j < 4; ++j){
      const int cout = wq*32 + mg*16 + (lane>>4)*4 + j;
      const float bv = b4[cout];
      #pragma unroll
      for (int ng = 0; ng < 4; ++ng){
        const int n = n0 + ng*16 + (lane & 15);
        float v = acc2[mg][ng][j] + bv; v = v > 0.f ? v : 0.f;
        h4[(size_t)cout*NTOT + n] = f2b(v);
      }
    }
}

// K6: transpose h0/c0 [B,128] -> [128][B]
__global__ __launch_bounds__(256) void k_init(
    const float* __restrict__ h0, const float* __restrict__ c0,
    float* __restrict__ hT0, float* __restrict__ cT)
{
  const int idx = blockIdx.x*256 + threadIdx.x;   // 1M
  const int b = idx >> 7, c = idx & 127;
  hT0[c*BATCH + b] = h0[idx];
  cT [c*BATCH + b] = c0[idx];
}

// ---------------------------------------------------------------------------
// K-GX: xg[512][32768] = Wih @ x for 4 steps (one half).
// ---------------------------------------------------------------------------
__global__ __launch_bounds__(256) void k_gatex(
    const bf16* __restrict__ h4, const bf16* __restrict__ wlx,
    float* __restrict__ xg, int half)
{
  __shared__ __align__(16) char Bs[32*256];
  const int tid = threadIdx.x, lane = tid & 63, wq = tid >> 6;
  const int n0 = blockIdx.x * 32;
  const int gcol = half*32768 + n0;

  for (int it = tid; it < 128*32; it += 256){
    const int cp = it >> 5, nl = it & 31;
    const bf16 v = h4[(size_t)cp*NTOT + gcol + nl];
    int off = nl*256 + cp*2; off ^= ((nl&7)<<4);
    *(short*)(Bs + off) = *(const short*)&v;
  }
  __syncthreads();

  f32x4 acc[8][2];
  #pragma unroll
  for (int mg = 0; mg < 8; ++mg)
    #pragma unroll
    for (int ng = 0; ng < 2; ++ng) acc[mg][ng] = f32x4{0.f,0.f,0.f,0.f};

  int arow[8];
  #pragma unroll
  for (int mg = 0; mg < 8; ++mg) arow[mg] = wq*128 + mg*16 + (lane & 15);
  const int kb = (lane>>4)*16;

  #pragma unroll
  for (int ks = 0; ks < 4; ++ks){
    short8 bfr[2];
    #pragma unroll
    for (int ng = 0; ng < 2; ++ng){
      const int row = ng*16 + (lane & 15);
      int off = row*256 + ks*64 + kb; off ^= ((row&7)<<4);
      bfr[ng] = *(const short8*)(Bs + off);
    }
    #pragma unroll
    for (int pl = 0; pl < 2; ++pl)
      #pragma unroll
      for (int mg = 0; mg < 8; ++mg){
        const short8 a = *(const short8*)((const char*)wlx +
            ((size_t)(pl*512 + arow[mg])*128 + ks*32)*2 + kb);
        #pragma unroll
        for (int ng = 0; ng < 2; ++ng)
          acc[mg][ng] = __builtin_amdgcn_mfma_f32_16x16x32_bf16(
              a, bfr[ng], acc[mg][ng], 0, 0, 0);
      }
  }

  #pragma unroll
  for (int mg = 0; mg < 8; ++mg)
    #pragma unroll
    for (int j = 0; j < 4; ++j){
      const int row = wq*128 + mg*16 + (lane>>4)*4 + j;
      #pragma unroll
      for (int ng = 0; ng < 2; ++ng){
        const int col = n0 + ng*16 + (lane & 15);
        xg[(size_t)row*32768 + col] = acc[mg][ng][j];
      }
    }
}

// ---------------------------------------------------------------------------
// K7 (validated r18): one recurrent LSTM step, Whh-only MFMA (K=384),
// 32 batch cols per block, 256 blocks.
// ---------------------------------------------------------------------------
__global__ __launch_bounds__(256) void k_lstm_rec(
    const float* __restrict__ xg, const bf16* __restrict__ wl3,
    const float* __restrict__ bih, const float* __restrict__ bhh,
    const float* __restrict__ hprev, float* __restrict__ hout,
    float* __restrict__ cT, int s)
{
  __shared__ __align__(16) char Bs[32*768];
  const int tid = threadIdx.x, lane = tid & 63, wq = tid >> 6;
  const int b0 = blockIdx.x * 32;

  for (int it = tid; it < 128*32; it += 256){
    const int cp = it >> 5, bl = it & 31;
    const float v = hprev[cp*BATCH + b0 + bl];
    const bf16 hi = f2b(v);
    const bf16 lo = f2b(v - b2f(hi));
    int off1 = bl*768 + cp*2;        off1 ^= ((bl&7)<<4);
    int off2 = bl*768 + (128+cp)*2;  off2 ^= ((bl&7)<<4);
    int off3 = bl*768 + (256+cp)*2;  off3 ^= ((bl&7)<<4);
    *(short*)(Bs + off1) = *(const short*)&hi;
    *(short*)(Bs + off2) = *(const short*)&lo;
    *(short*)(Bs + off3) = *(const short*)&hi;
  }
  __syncthreads();

  const int c0r = wq*32;
  f32x4 acc[4][2][2];
  #pragma unroll
  for (int g = 0; g < 4; ++g)
    #pragma unroll
    for (int h = 0; h < 2; ++h)
      #pragma unroll
      for (int ng = 0; ng < 2; ++ng) acc[g][h][ng] = f32x4{0.f,0.f,0.f,0.f};

  int arow[4][2];
  #pragma unroll
  for (int g = 0; g < 4; ++g)
    #pragma unroll
    for (int h = 0; h < 2; ++h)
      arow[g][h] = (g*128 + c0r + h*16 + (lane&15))*768 + (lane>>4)*16;

  #pragma unroll
  for (int ks = 0; ks < 12; ++ks){
    short8 bfr[2];
    #pragma unroll
    for (int ng = 0; ng < 2; ++ng){
      const int row = ng*16 + (lane & 15);
      int off = row*768 + ks*64 + (lane>>4)*16; off ^= ((row&7)<<4);
      bfr[ng] = *(const short8*)(Bs + off);
    }
    #pragma unroll
    for (int g = 0; g < 4; ++g)
      #pragma unroll
      for (int h = 0; h < 2; ++h){
        const short8 a = *(const short8*)((const char*)wl3 + arow[g][h] + ks*64);
        #pragma unroll
        for (int ng = 0; ng < 2; ++ng)
          acc[g][h][ng] = __builtin_amdgcn_mfma_f32_16x16x32_bf16(
              a, bfr[ng], acc[g][h][ng], 0, 0, 0);
      }
  }

  const size_t xcolbase = (size_t)(s & 3)*8192 + b0;
  #pragma unroll
  for (int h = 0; h < 2; ++h)
    #pragma unroll
    for (int ng = 0; ng < 2; ++ng)
      #pragma unroll
      for (int j = 0; j < 4; ++j){
        const int c = c0r + h*16 + (lane>>4)*4 + j;
        const int b = b0 + ng*16 + (lane & 15);
        const size_t xc = xcolbase + ng*16 + (lane & 15);
        const float ig = acc[0][h][ng][j] + xg[(size_t)(0*128+c)*32768 + xc] + bih[c]       + bhh[c];
        const float fg = acc[1][h][ng][j] + xg[(size_t)(1*128+c)*32768 + xc] + bih[128 + c] + bhh[128 + c];
        const float gg = acc[2][h][ng][j] + xg[(size_t)(2*128+c)*32768 + xc] + bih[256 + c] + bhh[256 + c];
        const float og = acc[3][h][ng][j] + xg[(size_t)(3*128+c)*32768 + xc] + bih[384 + c] + bhh[384 + c];
        const float cold = cT[c*BATCH + b];
        const float cn = sigf(fg)*cold + sigf(ig)*tanhfast(gg);
        const float hn = sigf(og)*tanhfast(cn);
        cT  [c*BATCH + b] = cn;
        hout[c*BATCH + b] = hn;
      }
}

// K8a: P[s][b] = sigmoid(ow . hseq[s][:,b] + ob)
__global__ __launch_bounds__(256) void k_headp(
    const float* __restrict__ hseq, const float* __restrict__ ow,
    const float* __restrict__ ob, float* __restrict__ P)
{
  const int idx = blockIdx.x*256 + threadIdx.x;   // 65536
  const int s = idx >> 13, b = idx & (BATCH-1);
  const float* hp = hseq + (size_t)s*HID*BATCH;
  float acc = ob[0];
  for (int c = 0; c < 128; ++c) acc += ow[c]*hp[c*BATCH + b];
  P[s*BATCH + b] = sigf(acc);
}
// K8b: final = 1 - prod(1 - P[s])
__global__ __launch_bounds__(256) void k_head2(
    const float* __restrict__ P, float* __restrict__ outp)
{
  const int b = blockIdx.x*256 + threadIdx.x;     // 8192
  float prod = 1.f;
  #pragma unroll
  for (int s = 0; s < 8; ++s) prod *= (1.f - P[s*BATCH + b]);
  outp[b] = 1.f - prod;
}

// K9: transpose h_fin, c_fin to [B,128] in d_out
__global__ __launch_bounds__(256) void k_outT(
    const float* __restrict__ h7, const float* __restrict__ cT,
    float* __restrict__ out)
{
  const int idx = blockIdx.x*256 + threadIdx.x;   // 1M
  const int b = idx >> 7, c = idx & 127;
  out[8192 + idx]           = h7[c*BATCH + b];
  out[8192 + 1048576 + idx] = cT[c*BATCH + b];
}

// ---------------------------------------------------------------------------
extern "C" void kernel_launch(void* const* d_in, const int* in_sizes, int n_in,
                              void* d_out, int out_size, void* d_ws, size_t ws_size,
                              hipStream_t stream)
{
  (void)in_sizes; (void)n_in; (void)out_size; (void)ws_size;
  const float* audio = (const float*)d_in[0];
  const float* h0    = (const float*)d_in[1];
  const float* c0    = (const float*)d_in[2];
  const float* stftw = (const float*)d_in[3];
  const float* w1 = (const float*)d_in[4];  const float* b1 = (const float*)d_in[5];
  const float* w2 = (const float*)d_in[6];  const float* b2 = (const float*)d_in[7];
  const float* w3 = (const float*)d_in[8];  const float* b3 = (const float*)d_in[9];
  const float* w4 = (const float*)d_in[10]; const float* b4 = (const float*)d_in[11];
  const float* wih = (const float*)d_in[12]; const float* whh = (const float*)d_in[13];
  const float* bih = (const float*)d_in[14]; const float* bhh = (const float*)d_in[15];
  const float* ow  = (const float*)d_in[16]; const float* ob  = (const float*)d_in[17];
  float* out = (float*)d_out;

  // Workspace schedule (validated r18):
  char* ws = (char*)d_ws;
  bf16*  mag  = (bf16*) (ws + 0);
  bf16*  w2b  = (bf16*) (ws + 0);
  bf16*  w3e  = (bf16*) (ws + 1048576);
  bf16*  w4e  = (bf16*) (ws + 1081344);
  bf16*  h4   = (bf16*) (ws + 8388608);
  float* xg   = (float*)(ws + 25165824);
  float* hseq = (float*)(ws + 92274688);
  float* hT0  = (float*)(ws + 125829120);
  float* cT   = (float*)(ws + 130023424);
  bf16*  h1   = (bf16*) (ws + 67633152);
  bf16*  Wbf  = (bf16*) (ws + 67633152);
  bf16*  h2   = (bf16*) (ws + 134742016);
  bf16*  w1b  = (bf16*) (ws + 134742016);
  bf16*  wl3  = (bf16*) (ws + 134742016);
  bf16*  wlx  = (bf16*) (ws + 135135232);
  float* Pbuf = (float*)(ws + 135397376);

  k_wcvt  <<<258, 256, 0, stream>>>(stftw, Wbf);
  k_w1cvt <<<480, 256, 0, stream>>>(w1, w1b);
  k_stft3<<<2048, 256, 0, stream>>>(audio, Wbf, mag);
  k_enc1_gemm<<<2048, 256, 0, stream>>>(mag, w1b, b1, h1);
  k_w2cvt <<<192, 256, 0, stream>>>(w2, w2b);           // after enc1: mag dead
  k_w34cvt<<<128, 256, 0, stream>>>(w3, w4, w3e, w4e);  // after enc1: mag dead
  k_enc2_gemm<<<2048, 256, 0, stream>>>(h1, w2b, b2, h2);
  k_init <<<4096, 256, 0, stream>>>(h0, c0, hT0, cT);   // after enc2: h1 dead
  k_enc34<<<1024, 256, 0, stream>>>(h2, w3e, b3, w4e, b4, h4);
  k_wlcvt3<<<768, 256, 0, stream>>>(whh, wl3);          // after enc34: h2 dead
  k_wlxcvt<<<512, 256, 0, stream>>>(wih, wlx);
  for (int half = 0; half < 2; ++half){
    k_gatex<<<1024, 256, 0, stream>>>(h4, wlx, xg, half);
    for (int q = 0; q < 4; ++q){
      const int s = half*4 + q;
      const float* hprev = (s == 0) ? hT0 : (hseq + (size_t)(s-1)*HID*BATCH);
      k_lstm_rec<<<256, 256, 0, stream>>>(xg, wl3, bih, bhh, hprev,
                                          hseq + (size_t)s*HID*BATCH, cT, s);
    }
  }
  k_headp<<<256, 256, 0, stream>>>(hseq, ow, ob, Pbuf);
  k_head2<<<32, 256, 0, stream>>>(Pbuf, out);
  k_outT<<<4096, 256, 0, stream>>>(hseq + (size_t)7*HID*BATCH, cT, out);
}